// Round 9
// baseline (464.161 us; speedup 1.0000x reference)
//
#include <hip/hip_runtime.h>
#include <math.h>

#define NEXP 32
#define NTOK 256
#define DIMD 768
#define DHID 2048
#define DBOT 256
#define DOUT 768
#define NSLOT 512
#define CHUNK 16

// ---------------- gate: logits -> top2 -> weights; init y with bl; zero z and A ----------------
__global__ __launch_bounds__(64) void gate_kernel(
    const float* __restrict__ x, const float* __restrict__ gw,
    const float* __restrict__ bl, float* __restrict__ y,
    int* __restrict__ topk_idx, float* __restrict__ topk_w,
    float* __restrict__ z, float* __restrict__ A) {
  const int n = blockIdx.x;
  const int l = threadIdx.x;
  {  // zero z slice (512 f) and A slice (4096 f) for this block
    const float4 zv = {0.f, 0.f, 0.f, 0.f};
    float4* zp = (float4*)(z + n * 512 + l * 8);
    zp[0] = zv; zp[1] = zv;
    float4* ap = (float4*)(A + (size_t)n * 4096 + l * 64);
#pragma unroll
    for (int j = 0; j < 16; j++) ap[j] = zv;
  }
  const float* xr = x + n * DIMD;
  float xs[12];
#pragma unroll
  for (int j = 0; j < 12; j++) xs[j] = xr[l + 64 * j];
  float logit[NEXP];
#pragma unroll
  for (int e = 0; e < NEXP; e++) {
    const float* g = gw + e * DIMD;
    float p = 0.f;
#pragma unroll
    for (int j = 0; j < 12; j++) p = fmaf(xs[j], g[l + 64 * j], p);
#pragma unroll
    for (int m = 1; m < 64; m <<= 1) p += __shfl_xor(p, m);
    logit[e] = p;
  }
  int i0 = 0; float m0 = logit[0];
#pragma unroll
  for (int e = 1; e < NEXP; e++) { if (logit[e] > m0) { m0 = logit[e]; i0 = e; } }
  int i1 = -1; float m1 = -3.4e38f;
#pragma unroll
  for (int e = 0; e < NEXP; e++) { if (e != i0 && logit[e] > m1) { m1 = logit[e]; i1 = e; } }
  const float e1 = expf(m1 - m0);
  const float w0 = 1.f / (1.f + e1);
  const float w1 = e1 * w0;
  if (l == 0) {
    topk_idx[2 * n] = i0; topk_idx[2 * n + 1] = i1;
    topk_w[2 * n] = w0;  topk_w[2 * n + 1] = w1;
  }
  const float* bl0 = bl + i0 * DOUT;
  const float* bl1 = bl + i1 * DOUT;
#pragma unroll
  for (int j = 0; j < 12; j++) {
    const int o = l + 64 * j;
    y[n * DOUT + o] = fmaf(w0, bl0[o], w1 * bl1[o]);
  }
}

// ---------------- build compact per-expert token lists (+ slot->expert map) ----------------
__global__ __launch_bounds__(256) void build_lists(
    const int* __restrict__ topk_idx, const float* __restrict__ topk_w,
    int* __restrict__ counts, int* __restrict__ offsets,
    int* __restrict__ tok_list, float* __restrict__ tok_wt,
    int* __restrict__ slot_expert) {
  __shared__ int cnt[NEXP], base[NEXP], fill[NEXP];
  const int t = threadIdx.x;
  if (t < NEXP) { cnt[t] = 0; fill[t] = 0; }
  __syncthreads();
  const int e0 = topk_idx[2 * t], e1 = topk_idx[2 * t + 1];
  atomicAdd(&cnt[e0], 1);
  atomicAdd(&cnt[e1], 1);
  __syncthreads();
  if (t == 0) { int s = 0; for (int i = 0; i < NEXP; i++) { base[i] = s; s += cnt[i]; } }
  __syncthreads();
  const int p0 = atomicAdd(&fill[e0], 1);
  tok_list[base[e0] + p0] = t; tok_wt[base[e0] + p0] = topk_w[2 * t];
  slot_expert[base[e0] + p0] = e0;
  const int p1 = atomicAdd(&fill[e1], 1);
  tok_list[base[e1] + p1] = t; tok_wt[base[e1] + p1] = topk_w[2 * t + 1];
  slot_expert[base[e1] + p1] = e1;
  if (t < NEXP) { counts[t] = cnt[t]; offsets[t] = base[t]; }
}

__device__ __forceinline__ float gelu_f(float v) {
  return 0.5f * v * (1.f + erff(v * 0.70710678118654752f));
}

// ---------------- bias + gelu pass: B = gelu(A + bias[e]); A = 0 ----------------
// one block per slot row (H = 2048): 256 thr x 8 f
__global__ __launch_bounds__(256) void gelu_pass(
    const float* __restrict__ A, const float* __restrict__ bias,
    float* __restrict__ Bout, float* __restrict__ Azero,
    const int* __restrict__ slot_expert) {
  const int slot = blockIdx.x;
  const int e = slot_expert[slot];
  const int c0 = threadIdx.x * 8;
  const float* ap = A + (size_t)slot * DHID + c0;
  const float* bp = bias + (size_t)e * DHID + c0;
  float* op = Bout + (size_t)slot * DHID + c0;
  float* zp = Azero + (size_t)slot * DHID + c0;
  const float4 zz = {0.f, 0.f, 0.f, 0.f};
#pragma unroll
  for (int j = 0; j < 8; j += 4) {
    const float4 a = *(const float4*)(ap + j);
    const float4 b = *(const float4*)(bp + j);
    float4 o;
    o.x = gelu_f(a.x + b.x); o.y = gelu_f(a.y + b.y);
    o.z = gelu_f(a.z + b.z); o.w = gelu_f(a.w + b.w);
    *(float4*)(op + j) = o;
    *(float4*)(zp + j) = zz;
  }
}

// ---------------- generic expert FF K-tile ----------------
// All layers: KB = 256 rows per block, 256-col tile, chunk = 16 tokens,
// fp32 atomicAdd accumulation into Out. Block = 256 thr = 4 waves =
// 2 colgroups(128 cols, 2 cols/lane) x 2 K-halves(128 rows).
// MODE 0: x(gather) @ W1 -> A (atomic; bias+gelu in separate pass)
// MODE 1: h1 @ W2 -> A (atomic)
// MODE 2: h2 @ W3 -> z (atomic, z pre-zeroed)
// MODE 3: (z + b3) @ Wl -> y (atomic, weighted scatter; y pre-init with bl)
// Occupancy: ~90 VGPR, 16 KB LDS -> ~4 blocks/CU (16 waves), barrier-free K-loop.
template <int MODE>
__global__ __launch_bounds__(256) void ff_kernel(
    const float* __restrict__ Ain, const float* __restrict__ W,
    const float* __restrict__ Bias, float* __restrict__ Out,
    const int* __restrict__ offsets, const int* __restrict__ counts,
    const int* __restrict__ tok_list, const float* __restrict__ tok_wt,
    int KTOT, int NCT, int INS, int coltiles) {
  __shared__ float act[CHUNK * 256];   // 16 KB, single buffer
  const int tid  = threadIdx.x;
  const int lane = tid & 63;
  const int wave = tid >> 6;
  const int cg   = wave & 1;    // colgroup (128 cols)
  const int kh   = wave >> 1;   // K-half (128 rows)
  const int e    = blockIdx.y;
  const int ct   = blockIdx.x % coltiles;
  const int kb   = blockIdx.x / coltiles;
  const int cnt  = counts[e];
  const int off  = offsets[e];
  const int cb   = ct * 256;
  const int wcol2 = cg * 128 + 2 * lane;
  const float* Wblk = W + ((size_t)e * KTOT + (size_t)kb * 256 + kh * 128) * NCT + cb + wcol2;

  for (int tc0 = 0; tc0 < cnt; tc0 += CHUNK) {
    const int tcn = min(CHUNK, cnt - tc0);
    // ---- stage act [16][256] ----
    if (MODE == 3) {
      // register staging with b3 fold: 256 thr x 16 f
      const int t  = tid >> 4;
      const int r0 = (tid & 15) * 16;
      const int slot = min(off + tc0 + t, NSLOT - 1);
      const float* src  = Ain + (size_t)slot * INS + r0;
      const float* bsrc = Bias + (size_t)e * KTOT + r0;
      float* dst = act + t * 256 + r0;
#pragma unroll
      for (int j = 0; j < 16; j += 4) {
        float4 v = *(const float4*)(src + j);
        const float4 bv = *(const float4*)(bsrc + j);
        v.x += bv.x; v.y += bv.y; v.z += bv.z; v.w += bv.w;
        *(float4*)(dst + j) = v;
      }
    } else {
      // one global_load_lds call per token row (1 KB each), 4 per wave
#pragma unroll
      for (int i = 0; i < 4; i++) {
        const int t = wave * 4 + i;
        const int slot = min(off + tc0 + t, NSLOT - 1);
        const int row  = (MODE == 0) ? tok_list[slot] : slot;
        const float* src = Ain + (size_t)row * INS + (size_t)kb * 256 + lane * 4;
        __builtin_amdgcn_global_load_lds(
            (const __attribute__((address_space(1))) void*)src,
            (__attribute__((address_space(3))) void*)(act + t * 256),
            16, 0, 0);
      }
    }
    __syncthreads();

    // ---- barrier-free K-loop: 32 groups of 4 rows in this wave's half ----
    float acc0[CHUNK], acc1[CHUNK];
#pragma unroll
    for (int t = 0; t < CHUNK; t++) { acc0[t] = 0.f; acc1[t] = 0.f; }
    float2 wbuf[4][4];
#pragma unroll
    for (int j = 0; j < 4; j++) {
      wbuf[0][j] = *(const float2*)(Wblk + (size_t)j * NCT);
      wbuf[1][j] = *(const float2*)(Wblk + (size_t)(4 + j) * NCT);
    }
#pragma unroll 4
    for (int g = 0; g < 32; ++g) {
      const int cur = g & 3;
      const int nxt = (g + 2) & 3;
      const int gp  = min(g + 2, 31);          // clamped tail prefetch (L2-hot)
      const float* wn = Wblk + (size_t)(4 * gp) * NCT;
#pragma unroll
      for (int j = 0; j < 4; j++) wbuf[nxt][j] = *(const float2*)(wn + (size_t)j * NCT);
      const float* bp = act + kh * 128 + 4 * g;
#pragma unroll
      for (int t = 0; t < CHUNK; t++) {
        const float4 xv = *(const float4*)(bp + t * 256);  // uniform LDS broadcast
        acc0[t] = fmaf(xv.x, wbuf[cur][0].x, acc0[t]);
        acc1[t] = fmaf(xv.x, wbuf[cur][0].y, acc1[t]);
        acc0[t] = fmaf(xv.y, wbuf[cur][1].x, acc0[t]);
        acc1[t] = fmaf(xv.y, wbuf[cur][1].y, acc1[t]);
        acc0[t] = fmaf(xv.z, wbuf[cur][2].x, acc0[t]);
        acc1[t] = fmaf(xv.z, wbuf[cur][2].y, acc1[t]);
        acc0[t] = fmaf(xv.w, wbuf[cur][3].x, acc0[t]);
        acc1[t] = fmaf(xv.w, wbuf[cur][3].y, acc1[t]);
      }
    }

    // ---- 2-way cross-half reduce via LDS (act dead), emit atomically ----
    __syncthreads();
    if (kh == 1) {
#pragma unroll
      for (int t = 0; t < CHUNK; t++) {
        act[t * 256 + wcol2]     = acc0[t];
        act[t * 256 + wcol2 + 1] = acc1[t];
      }
    }
    __syncthreads();
    if (kh == 0) {
      for (int t = 0; t < tcn; t++) {
        const float s0 = acc0[t] + act[t * 256 + wcol2];
        const float s1 = acc1[t] + act[t * 256 + wcol2 + 1];
        const int slot = off + tc0 + t;
        if (MODE <= 2) {
          atomicAdd(&Out[(size_t)slot * NCT + cb + wcol2], s0);
          atomicAdd(&Out[(size_t)slot * NCT + cb + wcol2 + 1], s1);
        } else {
          const int trow = tok_list[slot];
          const float wgt = tok_wt[slot];
          atomicAdd(&Out[(size_t)trow * NCT + cb + wcol2], wgt * s0);
          atomicAdd(&Out[(size_t)trow * NCT + cb + wcol2 + 1], wgt * s1);
        }
      }
    }
    __syncthreads();   // protect act before next chunk's staging
  }
}

extern "C" void kernel_launch(void* const* d_in, const int* in_sizes, int n_in,
                              void* d_out, int out_size, void* d_ws, size_t ws_size,
                              hipStream_t stream) {
  const float* x  = (const float*)d_in[0];
  const float* gw = (const float*)d_in[1];
  const float* W1 = (const float*)d_in[2];
  const float* b1 = (const float*)d_in[3];
  const float* W2 = (const float*)d_in[4];
  const float* b2 = (const float*)d_in[5];
  const float* W3 = (const float*)d_in[6];
  const float* b3 = (const float*)d_in[7];
  const float* Wl = (const float*)d_in[8];
  const float* bl = (const float*)d_in[9];
  float* y  = (float*)d_out;
  float* ws = (float*)d_ws;

  float* topk_w   = ws;                    // 512 f
  int*   topk_idx = (int*)(ws + 512);      // 512 i
  int*   counts   = (int*)(ws + 1024);     // 32 i
  int*   offsets  = (int*)(ws + 1056);     // 32 i
  int*   tok_list = (int*)(ws + 1088);     // 512 i
  float* tok_wt   = ws + 1600;             // 512 f
  int*   slot_exp = (int*)(ws + 2112);     // 512 i
  float* A = ws + 4096;                    // 512*2048 accumulator (pre-gelu)
  float* B = A + (size_t)NSLOT * DHID;     // 512*2048 activations (post-gelu)
  float* z = B + (size_t)NSLOT * DHID;     // 512*256

  gate_kernel<<<NTOK, 64, 0, stream>>>(x, gw, bl, y, topk_idx, topk_w, z, A);
  build_lists<<<1, 256, 0, stream>>>(topk_idx, topk_w, counts, offsets, tok_list, tok_wt, slot_exp);
  // L1: x @ W1 -> A (atomic over 3 K-tiles x 8 coltiles)
  ff_kernel<0><<<dim3(24, 32), 256, 0, stream>>>(x, W1, nullptr, A, offsets, counts,
                                                 tok_list, tok_wt, DIMD, DHID, DIMD, 8);
  gelu_pass<<<NSLOT, 256, 0, stream>>>(A, b1, B, A, slot_exp);   // B = gelu(A+b1); A = 0
  // L2: B @ W2 -> A (atomic over 8 K-tiles x 8 coltiles)
  ff_kernel<1><<<dim3(64, 32), 256, 0, stream>>>(B, W2, nullptr, A, offsets, counts,
                                                 tok_list, tok_wt, DHID, DHID, DHID, 8);
  gelu_pass<<<NSLOT, 256, 0, stream>>>(A, b2, B, A, slot_exp);   // B = gelu(A+b2); A = 0
  // L3: B @ W3 -> z (atomic over 8 K-tiles)
  ff_kernel<2><<<dim3(8, 32), 256, 0, stream>>>(B, W3, nullptr, z, offsets, counts,
                                                tok_list, tok_wt, DHID, DBOT, DHID, 1);
  // L4: (z+b3) @ Wl -> y (atomic weighted scatter, 3 coltiles)
  ff_kernel<3><<<dim3(3, 32), 256, 0, stream>>>(z, Wl, b3, y, offsets, counts,
                                                tok_list, tok_wt, DBOT, DOUT, DBOT, 3);
}

// Round 10
// 452.258 us; speedup vs baseline: 1.0263x; 1.0263x over previous
//
#include <hip/hip_runtime.h>
#include <math.h>

#define NEXP 32
#define NTOK 256
#define DIMD 768
#define DHID 2048
#define DBOT 256
#define DOUT 768
#define NSLOT 512

// ---------------- gate: logits -> top2 -> weights; init y with bl; zero z and A ----------------
__global__ __launch_bounds__(64) void gate_kernel(
    const float* __restrict__ x, const float* __restrict__ gw,
    const float* __restrict__ bl, float* __restrict__ y,
    int* __restrict__ topk_idx, float* __restrict__ topk_w,
    float* __restrict__ z, float* __restrict__ A) {
  const int n = blockIdx.x;
  const int l = threadIdx.x;
  {  // zero z slice (512 f) and A slice (4096 f) for this block
    const float4 zv = {0.f, 0.f, 0.f, 0.f};
    float4* zp = (float4*)(z + n * 512 + l * 8);
    zp[0] = zv; zp[1] = zv;
    float4* ap = (float4*)(A + (size_t)n * 4096 + l * 64);
#pragma unroll
    for (int j = 0; j < 16; j++) ap[j] = zv;
  }
  const float* xr = x + n * DIMD;
  float xs[12];
#pragma unroll
  for (int j = 0; j < 12; j++) xs[j] = xr[l + 64 * j];
  float logit[NEXP];
#pragma unroll
  for (int e = 0; e < NEXP; e++) {
    const float* g = gw + e * DIMD;
    float p = 0.f;
#pragma unroll
    for (int j = 0; j < 12; j++) p = fmaf(xs[j], g[l + 64 * j], p);
#pragma unroll
    for (int m = 1; m < 64; m <<= 1) p += __shfl_xor(p, m);
    logit[e] = p;
  }
  int i0 = 0; float m0 = logit[0];
#pragma unroll
  for (int e = 1; e < NEXP; e++) { if (logit[e] > m0) { m0 = logit[e]; i0 = e; } }
  int i1 = -1; float m1 = -3.4e38f;
#pragma unroll
  for (int e = 0; e < NEXP; e++) { if (e != i0 && logit[e] > m1) { m1 = logit[e]; i1 = e; } }
  const float e1 = expf(m1 - m0);
  const float w0 = 1.f / (1.f + e1);
  const float w1 = e1 * w0;
  if (l == 0) {
    topk_idx[2 * n] = i0; topk_idx[2 * n + 1] = i1;
    topk_w[2 * n] = w0;  topk_w[2 * n + 1] = w1;
  }
  const float* bl0 = bl + i0 * DOUT;
  const float* bl1 = bl + i1 * DOUT;
#pragma unroll
  for (int j = 0; j < 12; j++) {
    const int o = l + 64 * j;
    y[n * DOUT + o] = fmaf(w0, bl0[o], w1 * bl1[o]);
  }
}

// ---------------- build compact per-expert token lists (+ slot->expert map) ----------------
__global__ __launch_bounds__(256) void build_lists(
    const int* __restrict__ topk_idx, const float* __restrict__ topk_w,
    int* __restrict__ counts, int* __restrict__ offsets,
    int* __restrict__ tok_list, float* __restrict__ tok_wt,
    int* __restrict__ slot_expert) {
  __shared__ int cnt[NEXP], base[NEXP], fill[NEXP];
  const int t = threadIdx.x;
  if (t < NEXP) { cnt[t] = 0; fill[t] = 0; }
  __syncthreads();
  const int e0 = topk_idx[2 * t], e1 = topk_idx[2 * t + 1];
  atomicAdd(&cnt[e0], 1);
  atomicAdd(&cnt[e1], 1);
  __syncthreads();
  if (t == 0) { int s = 0; for (int i = 0; i < NEXP; i++) { base[i] = s; s += cnt[i]; } }
  __syncthreads();
  const int p0 = atomicAdd(&fill[e0], 1);
  tok_list[base[e0] + p0] = t; tok_wt[base[e0] + p0] = topk_w[2 * t];
  slot_expert[base[e0] + p0] = e0;
  const int p1 = atomicAdd(&fill[e1], 1);
  tok_list[base[e1] + p1] = t; tok_wt[base[e1] + p1] = topk_w[2 * t + 1];
  slot_expert[base[e1] + p1] = e1;
  if (t < NEXP) { counts[t] = cnt[t]; offsets[t] = base[t]; }
}

__device__ __forceinline__ float gelu_f(float v) {
  return 0.5f * v * (1.f + erff(v * 0.70710678118654752f));
}

// ---------------- bias + gelu pass: B = gelu(A + bias[e]); A = 0 ----------------
__global__ __launch_bounds__(256) void gelu_pass(
    const float* __restrict__ A, const float* __restrict__ bias,
    float* __restrict__ Bout, float* __restrict__ Azero,
    const int* __restrict__ slot_expert) {
  const int slot = blockIdx.x;
  const int e = slot_expert[slot];
  const int c0 = threadIdx.x * 8;
  const float* ap = A + (size_t)slot * DHID + c0;
  const float* bp = bias + (size_t)e * DHID + c0;
  float* op = Bout + (size_t)slot * DHID + c0;
  float* zp = Azero + (size_t)slot * DHID + c0;
  const float4 zz = {0.f, 0.f, 0.f, 0.f};
#pragma unroll
  for (int j = 0; j < 8; j += 4) {
    const float4 a = *(const float4*)(ap + j);
    const float4 b = *(const float4*)(bp + j);
    float4 o;
    o.x = gelu_f(a.x + b.x); o.y = gelu_f(a.y + b.y);
    o.z = gelu_f(a.z + b.z); o.w = gelu_f(a.w + b.w);
    *(float4*)(op + j) = o;
    *(float4*)(zp + j) = zz;
  }
}

// ---- shared staging: act_t[k][tok] transposed, 32 tokens, KR rows, zero-padded ----
// thread: tok = tid&31, kk = tid>>5 stages rows kk*16..kk*16+15 for its token.
// ds_write bank = tok -> 2-way (free). Reads are wave-uniform float4 broadcasts.
template <int KR, int GATHER>
__device__ __forceinline__ void stage_tr(
    float* __restrict__ act_t, const float* __restrict__ Ain, int INS,
    const int* __restrict__ tok_list, int off, int tc0, int tcn, int kbase,
    int tid, const float* __restrict__ bfold) {
  const int tok = tid & 31;
  const int kk  = tid >> 5;
  if (kk < (KR >> 4)) {
    float v[16];
    if (tok < tcn) {
      const int slot = off + tc0 + tok;
      const int row  = GATHER ? tok_list[slot] : slot;
      const float* src = Ain + (size_t)row * INS + kbase + kk * 16;
#pragma unroll
      for (int j = 0; j < 16; j += 4) {
        float4 q = *(const float4*)(src + j);
        if (bfold) {
          const float4 b = *(const float4*)(bfold + kbase + kk * 16 + j);
          q.x += b.x; q.y += b.y; q.z += b.z; q.w += b.w;
        }
        v[j] = q.x; v[j + 1] = q.y; v[j + 2] = q.z; v[j + 3] = q.w;
      }
    } else {
#pragma unroll
      for (int j = 0; j < 16; j++) v[j] = 0.f;
    }
#pragma unroll
    for (int j = 0; j < 16; j++) act_t[(kk * 16 + j) * 32 + tok] = v[j];
  }
}

// ---- the 32-token FMA row step: 8 uniform float4 LDS reads, 64 FMA ----
__device__ __forceinline__ void row_fma(
    const float* __restrict__ arow, float2 w, float* acc0, float* acc1) {
#pragma unroll
  for (int i = 0; i < 8; i++) {
    const float4 xv = *(const float4*)(arow + 4 * i);
    acc0[4 * i]     = fmaf(xv.x, w.x, acc0[4 * i]);
    acc1[4 * i]     = fmaf(xv.x, w.y, acc1[4 * i]);
    acc0[4 * i + 1] = fmaf(xv.y, w.x, acc0[4 * i + 1]);
    acc1[4 * i + 1] = fmaf(xv.y, w.y, acc1[4 * i + 1]);
    acc0[4 * i + 2] = fmaf(xv.z, w.x, acc0[4 * i + 2]);
    acc1[4 * i + 2] = fmaf(xv.z, w.y, acc1[4 * i + 2]);
    acc0[4 * i + 3] = fmaf(xv.w, w.x, acc0[4 * i + 3]);
    acc1[4 * i + 3] = fmaf(xv.w, w.y, acc1[4 * i + 3]);
  }
}

// ---------------- L1/L2: linear-stream FF, NCT=2048 ----------------
// Block = 512 thr, covers 1024 contiguous cols (2/lane-flat, f2); walks 256 rows
// sequentially -> 4 KB contiguous per row. atomicAdd into pre-zeroed A.
// MODE 0: x(gather) @ W1 -> A ;  MODE 1: B @ W2 -> A
template <int MODE>
__global__ __launch_bounds__(512, 2) void ff_lin(
    const float* __restrict__ Ain, const float* __restrict__ W,
    float* __restrict__ Out,
    const int* __restrict__ offsets, const int* __restrict__ counts,
    const int* __restrict__ tok_list,
    int KTOT, int INS) {
  __shared__ float act_t[256 * 32];   // 32 KB
  const int tid = threadIdx.x;
  const int e   = blockIdx.y;
  const int ct  = blockIdx.x & 1;
  const int kb  = blockIdx.x >> 1;
  const int cnt = counts[e];
  const int off = offsets[e];
  const int col = ct * 1024 + 2 * tid;
  const float* Wcol = W + ((size_t)e * KTOT + (size_t)kb * 256) * 2048 + col;

  for (int tc0 = 0; tc0 < cnt; tc0 += 32) {
    const int tcn = min(32, cnt - tc0);
    stage_tr<256, MODE == 0>(act_t, Ain, INS, tok_list, off, tc0, tcn,
                             kb * 256, tid, nullptr);
    __syncthreads();

    float acc0[32], acc1[32];
#pragma unroll
    for (int t = 0; t < 32; t++) { acc0[t] = 0.f; acc1[t] = 0.f; }
    float2 wbuf[4];
    wbuf[0] = *(const float2*)(Wcol);
    wbuf[1] = *(const float2*)(Wcol + 2048);
#pragma unroll 4
    for (int r = 0; r < 256; ++r) {
      const int cur = r & 3;
      const int nxt = (r + 2) & 3;
      const int rp  = min(r + 2, 255);
      wbuf[nxt] = *(const float2*)(Wcol + (size_t)rp * 2048);
      row_fma(act_t + r * 32, wbuf[cur], acc0, acc1);
    }
    __syncthreads();

#pragma unroll
    for (int t = 0; t < 32; t++) {
      if (t < tcn) {
        const int slot = off + tc0 + t;
        atomicAdd(&Out[(size_t)slot * 2048 + col], acc0[t]);
        atomicAdd(&Out[(size_t)slot * 2048 + col + 1], acc1[t]);
      }
    }
  }
}

// ---------------- L3: B @ W3 -> z, NCT=256 ----------------
// 512 thr = 4 row-subgroups x 128 thr (256 cols f2); each subgroup streams
// rows sg, sg+4, ... -> block covers rows ~sequentially, 1 KB contiguous/row.
__global__ __launch_bounds__(512, 2) void ff_bot(
    const float* __restrict__ Ain, const float* __restrict__ W,
    float* __restrict__ Out,
    const int* __restrict__ offsets, const int* __restrict__ counts) {
  __shared__ float act_t[256 * 32];   // 32 KB
  const int tid = threadIdx.x;
  const int e   = blockIdx.y;
  const int kb  = blockIdx.x;
  const int cnt = counts[e];
  const int off = offsets[e];
  const int sg  = tid >> 7;          // row subgroup 0..3
  const int lt  = tid & 127;
  const int col = 2 * lt;
  const float* Wcol = W + ((size_t)e * 2048 + (size_t)kb * 256) * 256 + col;

  for (int tc0 = 0; tc0 < cnt; tc0 += 32) {
    const int tcn = min(32, cnt - tc0);
    stage_tr<256, 0>(act_t, Ain, DHID, nullptr, off, tc0, tcn, kb * 256, tid, nullptr);
    __syncthreads();

    float acc0[32], acc1[32];
#pragma unroll
    for (int t = 0; t < 32; t++) { acc0[t] = 0.f; acc1[t] = 0.f; }
    float2 wbuf[4];
    wbuf[0] = *(const float2*)(Wcol + (size_t)sg * 256);
    wbuf[1] = *(const float2*)(Wcol + (size_t)(sg + 4) * 256);
#pragma unroll 4
    for (int i = 0; i < 64; ++i) {
      const int cur = i & 3;
      const int nxt = (i + 2) & 3;
      const int ip  = min(i + 2, 63);
      wbuf[nxt] = *(const float2*)(Wcol + (size_t)(sg + 4 * ip) * 256);
      row_fma(act_t + (sg + 4 * i) * 32, wbuf[cur], acc0, acc1);
    }
    __syncthreads();

#pragma unroll
    for (int t = 0; t < 32; t++) {
      if (t < tcn) {
        const int slot = off + tc0 + t;
        atomicAdd(&Out[(size_t)slot * DBOT + col], acc0[t]);
        atomicAdd(&Out[(size_t)slot * DBOT + col + 1], acc1[t]);
      }
    }
  }
}

// ---------------- L4: (z+b3) @ Wl -> y (weighted scatter), NCT=768 ----------------
// 384 thr cover 768 cols (f2); 128-row K-tiles (kb 0..1); 3 KB contiguous/row.
__global__ __launch_bounds__(384, 2) void ff_out(
    const float* __restrict__ Ain, const float* __restrict__ W,
    const float* __restrict__ b3, float* __restrict__ y,
    const int* __restrict__ offsets, const int* __restrict__ counts,
    const int* __restrict__ tok_list, const float* __restrict__ tok_wt) {
  __shared__ float act_t[128 * 32];   // 16 KB
  const int tid = threadIdx.x;
  const int e   = blockIdx.y;
  const int kb  = blockIdx.x;
  const int cnt = counts[e];
  const int off = offsets[e];
  const int col = 2 * tid;
  const float* Wcol = W + ((size_t)e * DBOT + (size_t)kb * 128) * 768 + col;
  const float* bfold = b3 + (size_t)e * DBOT;

  for (int tc0 = 0; tc0 < cnt; tc0 += 32) {
    const int tcn = min(32, cnt - tc0);
    stage_tr<128, 0>(act_t, Ain, DBOT, nullptr, off, tc0, tcn, kb * 128, tid, bfold);
    __syncthreads();

    float acc0[32], acc1[32];
#pragma unroll
    for (int t = 0; t < 32; t++) { acc0[t] = 0.f; acc1[t] = 0.f; }
    float2 wbuf[4];
    wbuf[0] = *(const float2*)(Wcol);
    wbuf[1] = *(const float2*)(Wcol + 768);
#pragma unroll 4
    for (int r = 0; r < 128; ++r) {
      const int cur = r & 3;
      const int nxt = (r + 2) & 3;
      const int rp  = min(r + 2, 127);
      wbuf[nxt] = *(const float2*)(Wcol + (size_t)rp * 768);
      row_fma(act_t + r * 32, wbuf[cur], acc0, acc1);
    }
    __syncthreads();

#pragma unroll
    for (int t = 0; t < 32; t++) {
      if (t < tcn) {
        const int slot = off + tc0 + t;
        const int trow = tok_list[slot];
        const float wgt = tok_wt[slot];
        atomicAdd(&y[(size_t)trow * DOUT + col], wgt * acc0[t]);
        atomicAdd(&y[(size_t)trow * DOUT + col + 1], wgt * acc1[t]);
      }
    }
  }
}

extern "C" void kernel_launch(void* const* d_in, const int* in_sizes, int n_in,
                              void* d_out, int out_size, void* d_ws, size_t ws_size,
                              hipStream_t stream) {
  const float* x  = (const float*)d_in[0];
  const float* gw = (const float*)d_in[1];
  const float* W1 = (const float*)d_in[2];
  const float* b1 = (const float*)d_in[3];
  const float* W2 = (const float*)d_in[4];
  const float* b2 = (const float*)d_in[5];
  const float* W3 = (const float*)d_in[6];
  const float* b3 = (const float*)d_in[7];
  const float* Wl = (const float*)d_in[8];
  const float* bl = (const float*)d_in[9];
  float* y  = (float*)d_out;
  float* ws = (float*)d_ws;

  float* topk_w   = ws;                    // 512 f
  int*   topk_idx = (int*)(ws + 512);      // 512 i
  int*   counts   = (int*)(ws + 1024);     // 32 i
  int*   offsets  = (int*)(ws + 1056);     // 32 i
  int*   tok_list = (int*)(ws + 1088);     // 512 i
  float* tok_wt   = ws + 1600;             // 512 f
  int*   slot_exp = (int*)(ws + 2112);     // 512 i
  float* A = ws + 4096;                    // 512*2048 accumulator (pre-gelu)
  float* B = A + (size_t)NSLOT * DHID;     // 512*2048 activations (post-gelu)
  float* z = B + (size_t)NSLOT * DHID;     // 512*256

  gate_kernel<<<NTOK, 64, 0, stream>>>(x, gw, bl, y, topk_idx, topk_w, z, A);
  build_lists<<<1, 256, 0, stream>>>(topk_idx, topk_w, counts, offsets, tok_list, tok_wt, slot_exp);
  // L1: x @ W1 -> A   (3 K-tiles x 2 col-halves x 32 experts = 192 blocks)
  ff_lin<0><<<dim3(6, 32), 512, 0, stream>>>(x, W1, A, offsets, counts, tok_list,
                                             DIMD, DIMD);
  gelu_pass<<<NSLOT, 256, 0, stream>>>(A, b1, B, A, slot_exp);   // B = gelu(A+b1); A = 0
  // L2: B @ W2 -> A   (8 K-tiles x 2 col-halves x 32 experts = 512 blocks)
  ff_lin<1><<<dim3(16, 32), 512, 0, stream>>>(B, W2, A, offsets, counts, tok_list,
                                              DHID, DHID);
  gelu_pass<<<NSLOT, 256, 0, stream>>>(A, b2, B, A, slot_exp);   // B = gelu(A+b2); A = 0
  // L3: B @ W3 -> z   (8 K-tiles x 32 experts = 256 blocks)
  ff_bot<<<dim3(8, 32), 512, 0, stream>>>(B, W3, z, offsets, counts);
  // L4: (z+b3) @ Wl -> y  (2 K-tiles x 32 experts = 64 blocks)
  ff_out<<<dim3(2, 32), 384, 0, stream>>>(z, Wl, b3, y, offsets, counts, tok_list, tok_wt);
}